// Round 3
// baseline (616.607 us; speedup 1.0000x reference)
//
#include <hip/hip_runtime.h>
#include <hip/hip_bf16.h>
#include <cstdint>

typedef __bf16 bf16;
typedef __bf16 bf16x8 __attribute__((ext_vector_type(8)));
typedef __bf16 bf16x4 __attribute__((ext_vector_type(4)));
typedef float floatx4 __attribute__((ext_vector_type(4)));

#define MFMA16(a, b, c) __builtin_amdgcn_mfma_f32_16x16x32_bf16(a, b, c, 0, 0, 0)

__device__ __forceinline__ void gload_lds16(const void* g, void* l) {
    __builtin_amdgcn_global_load_lds(
        (const __attribute__((address_space(1))) void*)g,
        (__attribute__((address_space(3))) void*)l, 16, 0, 0);
}

// ---------------------------------------------------------------------------
// fp32 -> bf16 flat downcast (n divisible by 1024)
// ---------------------------------------------------------------------------
__global__ void downcast_kernel(const float* __restrict__ in, bf16* __restrict__ out,
                                size_t n) {
    const size_t i = ((size_t)blockIdx.x * blockDim.x + threadIdx.x) * 4;
    if (i >= n) return;
    const float4 v = *(const float4*)(in + i);
    bf16x4 o = {(bf16)v.x, (bf16)v.y, (bf16)v.z, (bf16)v.w};
    *(bf16x4*)(out + i) = o;
}

// ---------------------------------------------------------------------------
// Transpose + downcast: in fp32 [R][C] -> out bf16 [C][R]
// ---------------------------------------------------------------------------
__global__ void transpose_kernel(const float* __restrict__ in, bf16* __restrict__ out,
                                 int R, int C) {
    __shared__ float tile[32][33];
    const int c0 = blockIdx.x * 32, r0 = blockIdx.y * 32;
    const int tx = threadIdx.x & 31, ty = threadIdx.x >> 5;  // ty in 0..7
    for (int i = 0; i < 32; i += 8)
        tile[ty + i][tx] = in[(size_t)(r0 + ty + i) * C + (c0 + tx)];
    __syncthreads();
    for (int i = 0; i < 32; i += 8)
        out[(size_t)(c0 + ty + i) * R + (r0 + tx)] = (bf16)tile[tx][ty + i];
}

// ---------------------------------------------------------------------------
// GEMM: C[M][N] = A[M][K] @ BT[N][K]^T   (bf16 in, fp32 accum)
// MODE 0: epilogue scatters to q/k/v   (N = 6144 = [3][16][128])
//   q -> qt[bh][s][hd] * HD^-0.5 ; k -> kt[bh][s][hd] ; v -> vt[bh][hd][s]
// MODE 1: epilogue writes FP32 C row-major [M][N]  (final output dtype)
// ---------------------------------------------------------------------------
template <int MODE>
__global__ __launch_bounds__(256) void gemm_bt_kernel(
    const bf16* __restrict__ A, const bf16* __restrict__ BT,
    int M, int N, int K,
    bf16* __restrict__ qt, bf16* __restrict__ kt, bf16* __restrict__ vt,
    float* __restrict__ Cout) {
    __shared__ alignas(16) bf16 As[128 * 32];
    __shared__ alignas(16) bf16 Bs[128 * 32];

    const int tid = threadIdx.x;
    const int wave = tid >> 6, lane = tid & 63;
    const int quad = lane >> 4, r16 = lane & 15;
    const int m0 = blockIdx.y * 128, n0 = blockIdx.x * 128;
    const int wm = (wave >> 1) * 64, wn = (wave & 1) * 64;

    floatx4 acc[4][4] = {};

    for (int k0 = 0; k0 < K; k0 += 32) {
        __syncthreads();
        {
            const int g0 = tid, g1 = tid + 256;
            const int ra = g0 >> 2, sa = g0 & 3;
            const int rb = g1 >> 2, sb = g1 & 3;
            gload_lds16(A + (size_t)(m0 + ra) * K + k0 + sa * 8, As + g0 * 8);
            gload_lds16(A + (size_t)(m0 + rb) * K + k0 + sb * 8, As + g1 * 8);
            gload_lds16(BT + (size_t)(n0 + ra) * K + k0 + sa * 8, Bs + g0 * 8);
            gload_lds16(BT + (size_t)(n0 + rb) * K + k0 + sb * 8, Bs + g1 * 8);
        }
        __syncthreads();

        bf16x8 a[4], b[4];
#pragma unroll
        for (int i = 0; i < 4; ++i)
            a[i] = *(const bf16x8*)(As + (wm + i * 16 + r16) * 32 + quad * 8);
#pragma unroll
        for (int j = 0; j < 4; ++j)
            b[j] = *(const bf16x8*)(Bs + (wn + j * 16 + r16) * 32 + quad * 8);
#pragma unroll
        for (int i = 0; i < 4; ++i)
#pragma unroll
            for (int j = 0; j < 4; ++j)
                acc[i][j] = MFMA16(a[i], b[j], acc[i][j]);
    }

    if (MODE == 0) {
        const int t = n0 >> 11;  // block-uniform: which of q/k/v
        const float qscale = 0.08838834764831845f;  // 128^-0.5
#pragma unroll
        for (int i = 0; i < 4; ++i) {
            const int mbase = m0 + wm + i * 16 + quad * 4;
            const int b_ = mbase >> 11;
            const int s = mbase & 2047;
#pragma unroll
            for (int j = 0; j < 4; ++j) {
                const int n = n0 + wn + j * 16 + r16;
                const int h = (n >> 7) & 15, hd = n & 127;
                const int bh = b_ * 16 + h;
                if (t == 0) {
#pragma unroll
                    for (int r = 0; r < 4; ++r)
                        qt[(size_t)(bh * 2048 + s + r) * 128 + hd] =
                            (bf16)(acc[i][j][r] * qscale);
                } else if (t == 1) {
#pragma unroll
                    for (int r = 0; r < 4; ++r)
                        kt[(size_t)(bh * 2048 + s + r) * 128 + hd] = (bf16)acc[i][j][r];
                } else {
                    bf16x4 pv = {(bf16)acc[i][j][0], (bf16)acc[i][j][1],
                                 (bf16)acc[i][j][2], (bf16)acc[i][j][3]};
                    *(bf16x4*)(vt + (size_t)(bh * 128 + hd) * 2048 + s) = pv;
                }
            }
        }
    } else {
#pragma unroll
        for (int i = 0; i < 4; ++i) {
            const int mbase = m0 + wm + i * 16 + quad * 4;
#pragma unroll
            for (int j = 0; j < 4; ++j) {
                const int n = n0 + wn + j * 16 + r16;
#pragma unroll
                for (int r = 0; r < 4; ++r)
                    Cout[(size_t)(mbase + r) * N + n] = acc[i][j][r];
            }
        }
    }
}

// ---------------------------------------------------------------------------
// Flash attention (causal). One block = (bh, 64 q-rows). 4 waves x 16 q-rows.
// qt/kt: [32][2048][128] bf16 (q pre-scaled); vt: [32][128][2048] bf16.
// o: [4096][2048] bf16 laid out [b*2048+s][h*128+hd]  (GEMM2 A-operand ready)
// ---------------------------------------------------------------------------
__global__ __launch_bounds__(256) void attn_kernel(
    const bf16* __restrict__ qt, const bf16* __restrict__ kt,
    const bf16* __restrict__ vt, bf16* __restrict__ o) {
    __shared__ alignas(16) bf16 Ks[32 * 128];   // [key][hd]
    __shared__ alignas(16) bf16 Vts[128 * 32];  // [hd][key]
    __shared__ alignas(16) bf16 Ps[4][16 * 32]; // per-wave P tile [qrow][key]

    const int tid = threadIdx.x;
    const int wave = tid >> 6, lane = tid & 63;
    const int quad = lane >> 4, r16 = lane & 15;
    const int qtile = blockIdx.x, bh = blockIdx.y;
    const int q0 = qtile * 64;
    const int qrow = q0 + wave * 16 + r16;  // A-operand m row for this lane

    // Q fragments (k-contiguous): held in registers for the whole kernel
    bf16x8 aq[4];
    const bf16* qbase = qt + (((size_t)bh * 2048 + qrow) << 7);
#pragma unroll
    for (int kc = 0; kc < 4; ++kc)
        aq[kc] = *(const bf16x8*)(qbase + kc * 32 + quad * 8);

    floatx4 oacc[8] = {};
    float mrow[4], lrow[4];
#pragma unroll
    for (int r = 0; r < 4; ++r) { mrow[r] = -1e30f; lrow[r] = 0.f; }

    const int niter = qtile * 2 + 2;  // causal: keys 0 .. q0+63
    for (int it = 0; it < niter; ++it) {
        const int k0 = it * 32;
        __syncthreads();
        {
            const int g0 = tid, g1 = tid + 256;
            // K tile [32][128]: row = g>>4, seg = g&15
            gload_lds16(kt + (((size_t)bh * 2048 + k0 + (g0 >> 4)) << 7) + (g0 & 15) * 8,
                        Ks + g0 * 8);
            gload_lds16(kt + (((size_t)bh * 2048 + k0 + (g1 >> 4)) << 7) + (g1 & 15) * 8,
                        Ks + g1 * 8);
            // Vt tile [128][32]: row = g>>2 (hd), seg = g&3
            gload_lds16(vt + ((size_t)bh * 128 + (g0 >> 2)) * 2048 + k0 + (g0 & 3) * 8,
                        Vts + g0 * 8);
            gload_lds16(vt + ((size_t)bh * 128 + (g1 >> 2)) * 2048 + k0 + (g1 & 3) * 8,
                        Vts + g1 * 8);
        }
        __syncthreads();

        // S = Q @ K^T : 16 q-rows x 32 keys per wave
        floatx4 sacc[2] = {};
#pragma unroll
        for (int nt = 0; nt < 2; ++nt)
#pragma unroll
            for (int kc = 0; kc < 4; ++kc) {
                bf16x8 bk = *(const bf16x8*)(Ks + (nt * 16 + r16) * 128 + kc * 32 + quad * 8);
                sacc[nt] = MFMA16(aq[kc], bk, sacc[nt]);
            }

        // causal mask + online softmax (rows = quad*4+r, cols = nt*16+r16)
        const int myq = q0 + wave * 16 + quad * 4;
        float pr[2][4], alpha[4];
#pragma unroll
        for (int r = 0; r < 4; ++r) {
            const int qq = myq + r;
            float s0 = (k0 + r16 <= qq) ? sacc[0][r] : -1e30f;
            float s1 = (k0 + 16 + r16 <= qq) ? sacc[1][r] : -1e30f;
            float v = fmaxf(s0, s1);
#pragma unroll
            for (int off = 8; off; off >>= 1) v = fmaxf(v, __shfl_xor(v, off));
            const float mn = fmaxf(mrow[r], v);
            const float al = __expf(mrow[r] - mn);
            const float p0 = __expf(s0 - mn);
            const float p1 = __expf(s1 - mn);
            float ps = p0 + p1;
#pragma unroll
            for (int off = 8; off; off >>= 1) ps += __shfl_xor(ps, off);
            lrow[r] = al * lrow[r] + ps;
            mrow[r] = mn;
            alpha[r] = al;
            pr[0][r] = p0;
            pr[1][r] = p1;
        }
#pragma unroll
        for (int nt2 = 0; nt2 < 8; ++nt2)
#pragma unroll
            for (int r = 0; r < 4; ++r) oacc[nt2][r] *= alpha[r];

        // P: C-layout -> LDS -> A-layout (bf16)
#pragma unroll
        for (int nt = 0; nt < 2; ++nt)
#pragma unroll
            for (int r = 0; r < 4; ++r)
                Ps[wave][(quad * 4 + r) * 32 + nt * 16 + r16] = (bf16)pr[nt][r];

        bf16x8 ap = *(const bf16x8*)(&Ps[wave][r16 * 32 + quad * 8]);
#pragma unroll
        for (int nt2 = 0; nt2 < 8; ++nt2) {
            bf16x8 bv = *(const bf16x8*)(Vts + (nt2 * 16 + r16) * 32 + quad * 8);
            oacc[nt2] = MFMA16(ap, bv, oacc[nt2]);
        }
    }

    // normalize + store (coalesced along r16 -> hd)
    const int b_ = bh >> 4, h = bh & 15;
#pragma unroll
    for (int r = 0; r < 4; ++r) {
        const int qq = q0 + wave * 16 + quad * 4 + r;
        const float inv = 1.0f / lrow[r];
        bf16* orow = o + (size_t)(b_ * 2048 + qq) * 2048 + h * 128;
#pragma unroll
        for (int nt2 = 0; nt2 < 8; ++nt2)
            orow[nt2 * 16 + r16] = (bf16)(oacc[nt2][r] * inv);
    }
}

// ---------------------------------------------------------------------------
extern "C" void kernel_launch(void* const* d_in, const int* in_sizes, int n_in,
                              void* d_out, int out_size, void* d_ws, size_t ws_size,
                              hipStream_t stream) {
    const float* x    = (const float*)d_in[0];  // [4096][2048] fp32
    const float* Wqkv = (const float*)d_in[1];  // [2048][6144] fp32
    const float* Wo   = (const float*)d_in[2];  // [2048][2048] fp32
    float* out        = (float*)d_out;          // [4096][2048] fp32

    char* ws = (char*)d_ws;
    bf16* xb    = (bf16*)ws; ws += (size_t)4096 * 2048 * 2;  // 16.8 MB
    bf16* WqkvT = (bf16*)ws; ws += (size_t)6144 * 2048 * 2;  // 25.2 MB
    bf16* WoT   = (bf16*)ws; ws += (size_t)2048 * 2048 * 2;  //  8.4 MB
    bf16* qt    = (bf16*)ws; ws += (size_t)32 * 2048 * 128 * 2;
    bf16* kt    = (bf16*)ws; ws += (size_t)32 * 2048 * 128 * 2;
    bf16* vt    = (bf16*)ws; ws += (size_t)32 * 128 * 2048 * 2;
    bf16* ob    = (bf16*)ws; ws += (size_t)4096 * 2048 * 2;

    downcast_kernel<<<8192, 256, 0, stream>>>(x, xb, (size_t)4096 * 2048);
    transpose_kernel<<<dim3(192, 64), 256, 0, stream>>>(Wqkv, WqkvT, 2048, 6144);
    transpose_kernel<<<dim3(64, 64), 256, 0, stream>>>(Wo, WoT, 2048, 2048);

    gemm_bt_kernel<0><<<dim3(48, 32), 256, 0, stream>>>(
        xb, WqkvT, 4096, 6144, 2048, qt, kt, vt, nullptr);

    attn_kernel<<<dim3(32, 32), 256, 0, stream>>>(qt, kt, vt, ob);

    gemm_bt_kernel<1><<<dim3(16, 32), 256, 0, stream>>>(
        ob, WoT, 4096, 2048, 2048, nullptr, nullptr, nullptr, out);
}

// Round 4
// 403.211 us; speedup vs baseline: 1.5292x; 1.5292x over previous
//
#include <hip/hip_runtime.h>
#include <hip/hip_bf16.h>
#include <cstdint>

typedef __bf16 bf16;
typedef __bf16 bf16x8 __attribute__((ext_vector_type(8)));
typedef __bf16 bf16x4 __attribute__((ext_vector_type(4)));
typedef float floatx4 __attribute__((ext_vector_type(4)));

#define MFMA16(a, b, c) __builtin_amdgcn_mfma_f32_16x16x32_bf16(a, b, c, 0, 0, 0)

__device__ __forceinline__ void gload_lds16(const void* g, void* l) {
    __builtin_amdgcn_global_load_lds(
        (const __attribute__((address_space(1))) void*)g,
        (__attribute__((address_space(3))) void*)l, 16, 0, 0);
}

// ---------------------------------------------------------------------------
// fp32 -> bf16 flat downcast
// ---------------------------------------------------------------------------
__global__ void downcast_kernel(const float* __restrict__ in, bf16* __restrict__ out,
                                size_t n) {
    const size_t i = ((size_t)blockIdx.x * blockDim.x + threadIdx.x) * 4;
    if (i >= n) return;
    const float4 v = *(const float4*)(in + i);
    bf16x4 o = {(bf16)v.x, (bf16)v.y, (bf16)v.z, (bf16)v.w};
    *(bf16x4*)(out + i) = o;
}

// ---------------------------------------------------------------------------
// Transpose + downcast: in fp32 [R][C] -> out bf16 [C][R]
// ---------------------------------------------------------------------------
__global__ void transpose_kernel(const float* __restrict__ in, bf16* __restrict__ out,
                                 int R, int C) {
    __shared__ float tile[32][33];
    const int c0 = blockIdx.x * 32, r0 = blockIdx.y * 32;
    const int tx = threadIdx.x & 31, ty = threadIdx.x >> 5;
    for (int i = 0; i < 32; i += 8)
        tile[ty + i][tx] = in[(size_t)(r0 + ty + i) * C + (c0 + tx)];
    __syncthreads();
    for (int i = 0; i < 32; i += 8)
        out[(size_t)(c0 + ty + i) * R + (r0 + tx)] = (bf16)tile[tx][ty + i];
}

// ---------------------------------------------------------------------------
// GEMM: C[M][N] = A[M][K] @ BT[N][K]^T   (bf16 in, fp32 accum)
// LDS tiles are XOR-swizzled at 16B-segment granularity:
//   position (row, sp) holds global segment s = (sp - ((row>>1)&3)) & 3
// so B-frag ds_read_b128 spreads across 8 bank-quads (2-way, free).
// ---------------------------------------------------------------------------
template <int MODE>
__global__ __launch_bounds__(256) void gemm_bt_kernel(
    const bf16* __restrict__ A, const bf16* __restrict__ BT,
    int M, int N, int K,
    bf16* __restrict__ qt, bf16* __restrict__ kt, bf16* __restrict__ vt,
    float* __restrict__ Cout) {
    __shared__ alignas(16) bf16 As[128 * 32];
    __shared__ alignas(16) bf16 Bs[128 * 32];

    const int tid = threadIdx.x;
    const int wave = tid >> 6, lane = tid & 63;
    const int quad = lane >> 4, r16 = lane & 15;
    const int m0 = blockIdx.y * 128, n0 = blockIdx.x * 128;
    const int wm = (wave >> 1) * 64, wn = (wave & 1) * 64;

    // chunk -> (row, swizzled seg) precompute for the two staged chunks/thread
    const int c0 = tid, c1 = tid + 256;
    const int ra = c0 >> 2, sa = ((c0 & 3) - ((ra >> 1) & 3)) & 3;
    const int rb = c1 >> 2, sb = ((c1 & 3) - ((rb >> 1) & 3)) & 3;

    floatx4 acc[4][4] = {};

    for (int k0 = 0; k0 < K; k0 += 32) {
        __syncthreads();
        gload_lds16(A + (size_t)(m0 + ra) * K + k0 + sa * 8, As + c0 * 8);
        gload_lds16(A + (size_t)(m0 + rb) * K + k0 + sb * 8, As + c1 * 8);
        gload_lds16(BT + (size_t)(n0 + ra) * K + k0 + sa * 8, Bs + c0 * 8);
        gload_lds16(BT + (size_t)(n0 + rb) * K + k0 + sb * 8, Bs + c1 * 8);
        __syncthreads();

        bf16x8 a[4], b[4];
#pragma unroll
        for (int i = 0; i < 4; ++i) {
            const int row = wm + i * 16 + r16;
            const int sp = (quad + ((row >> 1) & 3)) & 3;
            a[i] = *(const bf16x8*)(As + row * 32 + sp * 8);
        }
#pragma unroll
        for (int j = 0; j < 4; ++j) {
            const int row = wn + j * 16 + r16;
            const int sp = (quad + ((row >> 1) & 3)) & 3;
            b[j] = *(const bf16x8*)(Bs + row * 32 + sp * 8);
        }
#pragma unroll
        for (int i = 0; i < 4; ++i)
#pragma unroll
            for (int j = 0; j < 4; ++j)
                acc[i][j] = MFMA16(a[i], b[j], acc[i][j]);
    }

    if (MODE == 0) {
        const int t = n0 >> 11;  // block-uniform: which of q/k/v
        const float qscale = 0.08838834764831845f;  // 128^-0.5
#pragma unroll
        for (int i = 0; i < 4; ++i) {
            const int mbase = m0 + wm + i * 16 + quad * 4;
            const int b_ = mbase >> 11;
            const int s = mbase & 2047;
#pragma unroll
            for (int j = 0; j < 4; ++j) {
                const int n = n0 + wn + j * 16 + r16;
                const int h = (n >> 7) & 15, hd = n & 127;
                const int bh = b_ * 16 + h;
                if (t == 0) {
#pragma unroll
                    for (int r = 0; r < 4; ++r)
                        qt[(size_t)(bh * 2048 + s + r) * 128 + hd] =
                            (bf16)(acc[i][j][r] * qscale);
                } else if (t == 1) {
#pragma unroll
                    for (int r = 0; r < 4; ++r)
                        kt[(size_t)(bh * 2048 + s + r) * 128 + hd] = (bf16)acc[i][j][r];
                } else {
                    bf16x4 pv = {(bf16)acc[i][j][0], (bf16)acc[i][j][1],
                                 (bf16)acc[i][j][2], (bf16)acc[i][j][3]};
                    *(bf16x4*)(vt + (size_t)(bh * 128 + hd) * 2048 + s) = pv;
                }
            }
        }
    } else {
#pragma unroll
        for (int i = 0; i < 4; ++i) {
            const int mbase = m0 + wm + i * 16 + quad * 4;
#pragma unroll
            for (int j = 0; j < 4; ++j) {
                const int n = n0 + wn + j * 16 + r16;
#pragma unroll
                for (int r = 0; r < 4; ++r)
                    Cout[(size_t)(mbase + r) * N + n] = acc[i][j][r];
            }
        }
    }
}

// ---------------------------------------------------------------------------
// Flash attention (causal), no-max softmax, work-paired.
// Grid: (16 pairs, 32 bh). Block p does q-tiles {p, 31-p} (64 rows each)
// -> every block runs exactly 33 64-key iterations (balanced).
// 4 waves x 16 q-rows. BN=64. Diagonal-only masking.
// LDS K/V tiles XOR-swizzled at 16B segments; Ps row stride 72 (16B-aligned).
// ---------------------------------------------------------------------------
__global__ __launch_bounds__(256) void attn_kernel(
    const bf16* __restrict__ qt, const bf16* __restrict__ kt,
    const bf16* __restrict__ vt, bf16* __restrict__ o) {
    __shared__ alignas(16) bf16 Ks[64 * 128];    // (row, sp): seg = sp ^ (row&15)
    __shared__ alignas(16) bf16 Vts[128 * 64];   // (row, sp): seg = sp ^ (row&7)
    __shared__ alignas(16) bf16 Ps[4][16 * 72];  // per-wave P [row][key], stride 72

    const int tid = threadIdx.x;
    const int wave = tid >> 6, lane = tid & 63;
    const int quad = lane >> 4, r16 = lane & 15;
    const int pair = blockIdx.x, bh = blockIdx.y;
    const int b_ = bh >> 4, h = bh & 15;

    for (int half = 0; half < 2; ++half) {
        const int t = half == 0 ? pair : 31 - pair;
        const int q0 = t * 64;

        // Q A-frags: row m = r16 within wave tile
        bf16x8 aq[4];
        {
            const bf16* qbase = qt + (((size_t)bh * 2048 + q0 + wave * 16 + r16) << 7);
#pragma unroll
            for (int kc = 0; kc < 4; ++kc)
                aq[kc] = *(const bf16x8*)(qbase + kc * 32 + quad * 8);
        }

        floatx4 oacc[8] = {};
        float lsum[4] = {0.f, 0.f, 0.f, 0.f};

        for (int it = 0; it <= t; ++it) {
            const int k0 = it * 64;
            __syncthreads();
            // stage K [64][128]: 1024 16B chunks, swizzled
#pragma unroll
            for (int j = 0; j < 4; ++j) {
                const int c = tid + j * 256;
                const int row = c >> 4, sp = c & 15, s = sp ^ (row & 15);
                gload_lds16(kt + (((size_t)bh * 2048 + k0 + row) << 7) + s * 8,
                            Ks + c * 8);
            }
            // stage Vt [128][64]: 1024 16B chunks, swizzled
#pragma unroll
            for (int j = 0; j < 4; ++j) {
                const int c = tid + j * 256;
                const int row = c >> 3, sp = c & 7, s = sp ^ (row & 7);
                gload_lds16(vt + ((size_t)bh * 128 + row) * 2048 + k0 + s * 8,
                            Vts + c * 8);
            }
            __syncthreads();

            // S = Q @ K^T : 16 q-rows x 64 keys
            floatx4 sacc[4] = {};
#pragma unroll
            for (int nt = 0; nt < 4; ++nt) {
                const int row = nt * 16 + r16;
#pragma unroll
                for (int kc = 0; kc < 4; ++kc) {
                    const int sp = (4 * kc + quad) ^ r16;  // row&15 == r16
                    bf16x8 bk = *(const bf16x8*)(Ks + row * 128 + sp * 8);
                    sacc[nt] = MFMA16(aq[kc], bk, sacc[nt]);
                }
            }

            // exp (no max subtraction); mask only on the diagonal iteration
            const int qrowC = q0 + wave * 16 + quad * 4;
            float p[4][4];
            if (it == t) {
#pragma unroll
                for (int nt = 0; nt < 4; ++nt)
#pragma unroll
                    for (int r = 0; r < 4; ++r) {
                        const bool ok = (k0 + nt * 16 + r16) <= (qrowC + r);
                        const float e = ok ? __expf(sacc[nt][r]) : 0.f;
                        p[nt][r] = e;
                        lsum[r] += e;
                    }
            } else {
#pragma unroll
                for (int nt = 0; nt < 4; ++nt)
#pragma unroll
                    for (int r = 0; r < 4; ++r) {
                        const float e = __expf(sacc[nt][r]);
                        p[nt][r] = e;
                        lsum[r] += e;
                    }
            }

            // P: C-layout -> per-wave LDS (row stride 72) -> A-layout
#pragma unroll
            for (int nt = 0; nt < 4; ++nt)
#pragma unroll
                for (int r = 0; r < 4; ++r)
                    Ps[wave][(quad * 4 + r) * 72 + nt * 16 + r16] = (bf16)p[nt][r];

            // O += P @ V : PV over 64 keys = 2 k-blocks of 32
#pragma unroll
            for (int kblk = 0; kblk < 2; ++kblk) {
                bf16x8 ap = *(const bf16x8*)(&Ps[wave][r16 * 72 + kblk * 32 + quad * 8]);
#pragma unroll
                for (int nt2 = 0; nt2 < 8; ++nt2) {
                    const int row = nt2 * 16 + r16;
                    const int sp = (4 * kblk + quad) ^ (row & 7);
                    bf16x8 bv = *(const bf16x8*)(Vts + row * 64 + sp * 8);
                    oacc[nt2] = MFMA16(ap, bv, oacc[nt2]);
                }
            }
        }

        // one deferred l-reduction per tile: sum across r16 within quad group
#pragma unroll
        for (int r = 0; r < 4; ++r) {
            float s = lsum[r];
#pragma unroll
            for (int off = 1; off < 16; off <<= 1) s += __shfl_xor(s, off);
            lsum[r] = s;
        }

        // normalize + store (coalesced along r16 -> hd)
#pragma unroll
        for (int r = 0; r < 4; ++r) {
            const int qq = q0 + wave * 16 + quad * 4 + r;
            const float inv = 1.0f / lsum[r];
            bf16* orow = o + (size_t)(b_ * 2048 + qq) * 2048 + h * 128;
#pragma unroll
            for (int nt2 = 0; nt2 < 8; ++nt2)
                orow[nt2 * 16 + r16] = (bf16)(oacc[nt2][r] * inv);
        }
    }
}

// ---------------------------------------------------------------------------
extern "C" void kernel_launch(void* const* d_in, const int* in_sizes, int n_in,
                              void* d_out, int out_size, void* d_ws, size_t ws_size,
                              hipStream_t stream) {
    const float* x    = (const float*)d_in[0];  // [4096][2048] fp32
    const float* Wqkv = (const float*)d_in[1];  // [2048][6144] fp32
    const float* Wo   = (const float*)d_in[2];  // [2048][2048] fp32
    float* out        = (float*)d_out;          // [4096][2048] fp32

    char* ws = (char*)d_ws;
    bf16* xb    = (bf16*)ws; ws += (size_t)4096 * 2048 * 2;
    bf16* WqkvT = (bf16*)ws; ws += (size_t)6144 * 2048 * 2;
    bf16* WoT   = (bf16*)ws; ws += (size_t)2048 * 2048 * 2;
    bf16* qt    = (bf16*)ws; ws += (size_t)32 * 2048 * 128 * 2;
    bf16* kt    = (bf16*)ws; ws += (size_t)32 * 2048 * 128 * 2;
    bf16* vt    = (bf16*)ws; ws += (size_t)32 * 128 * 2048 * 2;
    bf16* ob    = (bf16*)ws; ws += (size_t)4096 * 2048 * 2;

    downcast_kernel<<<8192, 256, 0, stream>>>(x, xb, (size_t)4096 * 2048);
    transpose_kernel<<<dim3(192, 64), 256, 0, stream>>>(Wqkv, WqkvT, 2048, 6144);
    transpose_kernel<<<dim3(64, 64), 256, 0, stream>>>(Wo, WoT, 2048, 2048);

    gemm_bt_kernel<0><<<dim3(48, 32), 256, 0, stream>>>(
        xb, WqkvT, 4096, 6144, 2048, qt, kt, vt, nullptr);

    attn_kernel<<<dim3(16, 32), 256, 0, stream>>>(qt, kt, vt, ob);

    gemm_bt_kernel<1><<<dim3(16, 32), 256, 0, stream>>>(
        ob, WoT, 4096, 2048, 2048, nullptr, nullptr, nullptr, out);
}

// Round 5
// 375.147 us; speedup vs baseline: 1.6436x; 1.0748x over previous
//
#include <hip/hip_runtime.h>
#include <hip/hip_bf16.h>
#include <cstdint>

typedef __bf16 bf16;
typedef __bf16 bf16x8 __attribute__((ext_vector_type(8)));
typedef __bf16 bf16x4 __attribute__((ext_vector_type(4)));
typedef float floatx4 __attribute__((ext_vector_type(4)));

#define MFMA16(a, b, c) __builtin_amdgcn_mfma_f32_16x16x32_bf16(a, b, c, 0, 0, 0)

__device__ __forceinline__ void gload_lds16(const void* g, void* l) {
    __builtin_amdgcn_global_load_lds(
        (const __attribute__((address_space(1))) void*)g,
        (__attribute__((address_space(3))) void*)l, 16, 0, 0);
}

// ---------------------------------------------------------------------------
// fp32 -> bf16 flat downcast
// ---------------------------------------------------------------------------
__global__ void downcast_kernel(const float* __restrict__ in, bf16* __restrict__ out,
                                size_t n) {
    const size_t i = ((size_t)blockIdx.x * blockDim.x + threadIdx.x) * 4;
    if (i >= n) return;
    const float4 v = *(const float4*)(in + i);
    bf16x4 o = {(bf16)v.x, (bf16)v.y, (bf16)v.z, (bf16)v.w};
    *(bf16x4*)(out + i) = o;
}

// ---------------------------------------------------------------------------
// Transpose + downcast: in fp32 [R][C] -> out bf16 [C][R]
// ---------------------------------------------------------------------------
__global__ void transpose_kernel(const float* __restrict__ in, bf16* __restrict__ out,
                                 int R, int C) {
    __shared__ float tile[32][33];
    const int c0 = blockIdx.x * 32, r0 = blockIdx.y * 32;
    const int tx = threadIdx.x & 31, ty = threadIdx.x >> 5;
    for (int i = 0; i < 32; i += 8)
        tile[ty + i][tx] = in[(size_t)(r0 + ty + i) * C + (c0 + tx)];
    __syncthreads();
    for (int i = 0; i < 32; i += 8)
        out[(size_t)(c0 + ty + i) * R + (r0 + tx)] = (bf16)tile[tx][ty + i];
}

// ---------------------------------------------------------------------------
// GEMM: C[M][N] = A[M][K] @ BT[N][K]^T   (bf16 in, fp32 accum)
// BK=64: 32 MFMA + 16 ds_read_b128 per barrier pair (halves barrier drains
// vs BK=32). LDS rows are 8 x 16B segments, XOR-swizzled: position (row,sp)
// holds global segment s = sp ^ (row&7)  -> frag ds_read_b128 is 2-way (free).
// MODE 0: epilogue scatters to q/k/v (N = 6144 = [3][16][128])
// MODE 1: epilogue writes FP32 C row-major [M][N]
// ---------------------------------------------------------------------------
template <int MODE>
__global__ __launch_bounds__(256) void gemm_bt_kernel(
    const bf16* __restrict__ A, const bf16* __restrict__ BT,
    int M, int N, int K,
    bf16* __restrict__ qt, bf16* __restrict__ kt, bf16* __restrict__ vt,
    float* __restrict__ Cout) {
    __shared__ alignas(16) bf16 As[128 * 64];  // 16 KB
    __shared__ alignas(16) bf16 Bs[128 * 64];  // 16 KB

    const int tid = threadIdx.x;
    const int wave = tid >> 6, lane = tid & 63;
    const int quad = lane >> 4, r16 = lane & 15;
    const int m0 = blockIdx.y * 128, n0 = blockIdx.x * 128;
    const int wm = (wave >> 1) * 64, wn = (wave & 1) * 64;

    // staging map: 4 chunks per matrix per thread; chunk c: row=c>>3, sp=c&7,
    // global seg s = sp ^ (row&7)
    int srow[4], soff[4];
#pragma unroll
    for (int j = 0; j < 4; ++j) {
        const int c = tid + j * 256;
        srow[j] = c >> 3;
        soff[j] = ((c & 7) ^ (srow[j] & 7)) * 8;
    }

    floatx4 acc[4][4] = {};

    for (int k0 = 0; k0 < K; k0 += 64) {
        __syncthreads();
#pragma unroll
        for (int j = 0; j < 4; ++j) {
            const int c = tid + j * 256;
            gload_lds16(A + (size_t)(m0 + srow[j]) * K + k0 + soff[j], As + c * 8);
            gload_lds16(BT + (size_t)(n0 + srow[j]) * K + k0 + soff[j], Bs + c * 8);
        }
        __syncthreads();

#pragma unroll
        for (int kc = 0; kc < 2; ++kc) {
            bf16x8 a[4], b[4];
#pragma unroll
            for (int i = 0; i < 4; ++i) {
                const int row = wm + i * 16 + r16;
                const int sp = (4 * kc + quad) ^ (row & 7);
                a[i] = *(const bf16x8*)(As + row * 64 + sp * 8);
            }
#pragma unroll
            for (int j = 0; j < 4; ++j) {
                const int row = wn + j * 16 + r16;
                const int sp = (4 * kc + quad) ^ (row & 7);
                b[j] = *(const bf16x8*)(Bs + row * 64 + sp * 8);
            }
#pragma unroll
            for (int i = 0; i < 4; ++i)
#pragma unroll
                for (int j = 0; j < 4; ++j)
                    acc[i][j] = MFMA16(a[i], b[j], acc[i][j]);
        }
    }

    if (MODE == 0) {
        const int t = n0 >> 11;  // block-uniform: which of q/k/v
        const float qscale = 0.08838834764831845f;  // 128^-0.5
#pragma unroll
        for (int i = 0; i < 4; ++i) {
            const int mbase = m0 + wm + i * 16 + quad * 4;
            const int b_ = mbase >> 11;
            const int s = mbase & 2047;
#pragma unroll
            for (int j = 0; j < 4; ++j) {
                const int n = n0 + wn + j * 16 + r16;
                const int h = (n >> 7) & 15, hd = n & 127;
                const int bh = b_ * 16 + h;
                if (t == 0) {
#pragma unroll
                    for (int r = 0; r < 4; ++r)
                        qt[(size_t)(bh * 2048 + s + r) * 128 + hd] =
                            (bf16)(acc[i][j][r] * qscale);
                } else if (t == 1) {
#pragma unroll
                    for (int r = 0; r < 4; ++r)
                        kt[(size_t)(bh * 2048 + s + r) * 128 + hd] = (bf16)acc[i][j][r];
                } else {
                    bf16x4 pv = {(bf16)acc[i][j][0], (bf16)acc[i][j][1],
                                 (bf16)acc[i][j][2], (bf16)acc[i][j][3]};
                    *(bf16x4*)(vt + (size_t)(bh * 128 + hd) * 2048 + s) = pv;
                }
            }
        }
    } else {
#pragma unroll
        for (int i = 0; i < 4; ++i) {
            const int mbase = m0 + wm + i * 16 + quad * 4;
#pragma unroll
            for (int j = 0; j < 4; ++j) {
                const int n = n0 + wn + j * 16 + r16;
#pragma unroll
                for (int r = 0; r < 4; ++r)
                    Cout[(size_t)(mbase + r) * N + n] = acc[i][j][r];
            }
        }
    }
}

// ---------------------------------------------------------------------------
// Flash attention (causal), no-max softmax, work-paired. (unchanged from R4)
// Grid: (16 pairs, 32 bh). Block p does q-tiles {p, 31-p} (64 rows each).
// 4 waves x 16 q-rows. BN=64. Diagonal-only masking.
// LDS K/V tiles XOR-swizzled at 16B segments; Ps row stride 72.
// ---------------------------------------------------------------------------
__global__ __launch_bounds__(256) void attn_kernel(
    const bf16* __restrict__ qt, const bf16* __restrict__ kt,
    const bf16* __restrict__ vt, bf16* __restrict__ o) {
    __shared__ alignas(16) bf16 Ks[64 * 128];    // (row, sp): seg = sp ^ (row&15)
    __shared__ alignas(16) bf16 Vts[128 * 64];   // (row, sp): seg = sp ^ (row&7)
    __shared__ alignas(16) bf16 Ps[4][16 * 72];  // per-wave P [row][key], stride 72

    const int tid = threadIdx.x;
    const int wave = tid >> 6, lane = tid & 63;
    const int quad = lane >> 4, r16 = lane & 15;
    const int pair = blockIdx.x, bh = blockIdx.y;
    const int b_ = bh >> 4, h = bh & 15;

    for (int half = 0; half < 2; ++half) {
        const int t = half == 0 ? pair : 31 - pair;
        const int q0 = t * 64;

        bf16x8 aq[4];
        {
            const bf16* qbase = qt + (((size_t)bh * 2048 + q0 + wave * 16 + r16) << 7);
#pragma unroll
            for (int kc = 0; kc < 4; ++kc)
                aq[kc] = *(const bf16x8*)(qbase + kc * 32 + quad * 8);
        }

        floatx4 oacc[8] = {};
        float lsum[4] = {0.f, 0.f, 0.f, 0.f};

        for (int it = 0; it <= t; ++it) {
            const int k0 = it * 64;
            __syncthreads();
#pragma unroll
            for (int j = 0; j < 4; ++j) {
                const int c = tid + j * 256;
                const int row = c >> 4, sp = c & 15, s = sp ^ (row & 15);
                gload_lds16(kt + (((size_t)bh * 2048 + k0 + row) << 7) + s * 8,
                            Ks + c * 8);
            }
#pragma unroll
            for (int j = 0; j < 4; ++j) {
                const int c = tid + j * 256;
                const int row = c >> 3, sp = c & 7, s = sp ^ (row & 7);
                gload_lds16(vt + ((size_t)bh * 128 + row) * 2048 + k0 + s * 8,
                            Vts + c * 8);
            }
            __syncthreads();

            floatx4 sacc[4] = {};
#pragma unroll
            for (int nt = 0; nt < 4; ++nt) {
                const int row = nt * 16 + r16;
#pragma unroll
                for (int kc = 0; kc < 4; ++kc) {
                    const int sp = (4 * kc + quad) ^ r16;
                    bf16x8 bk = *(const bf16x8*)(Ks + row * 128 + sp * 8);
                    sacc[nt] = MFMA16(aq[kc], bk, sacc[nt]);
                }
            }

            const int qrowC = q0 + wave * 16 + quad * 4;
            float p[4][4];
            if (it == t) {
#pragma unroll
                for (int nt = 0; nt < 4; ++nt)
#pragma unroll
                    for (int r = 0; r < 4; ++r) {
                        const bool ok = (k0 + nt * 16 + r16) <= (qrowC + r);
                        const float e = ok ? __expf(sacc[nt][r]) : 0.f;
                        p[nt][r] = e;
                        lsum[r] += e;
                    }
            } else {
#pragma unroll
                for (int nt = 0; nt < 4; ++nt)
#pragma unroll
                    for (int r = 0; r < 4; ++r) {
                        const float e = __expf(sacc[nt][r]);
                        p[nt][r] = e;
                        lsum[r] += e;
                    }
            }

#pragma unroll
            for (int nt = 0; nt < 4; ++nt)
#pragma unroll
                for (int r = 0; r < 4; ++r)
                    Ps[wave][(quad * 4 + r) * 72 + nt * 16 + r16] = (bf16)p[nt][r];

#pragma unroll
            for (int kblk = 0; kblk < 2; ++kblk) {
                bf16x8 ap = *(const bf16x8*)(&Ps[wave][r16 * 72 + kblk * 32 + quad * 8]);
#pragma unroll
                for (int nt2 = 0; nt2 < 8; ++nt2) {
                    const int row = nt2 * 16 + r16;
                    const int sp = (4 * kblk + quad) ^ (row & 7);
                    bf16x8 bv = *(const bf16x8*)(Vts + row * 64 + sp * 8);
                    oacc[nt2] = MFMA16(ap, bv, oacc[nt2]);
                }
            }
        }

#pragma unroll
        for (int r = 0; r < 4; ++r) {
            float s = lsum[r];
#pragma unroll
            for (int off = 1; off < 16; off <<= 1) s += __shfl_xor(s, off);
            lsum[r] = s;
        }

#pragma unroll
        for (int r = 0; r < 4; ++r) {
            const int qq = q0 + wave * 16 + quad * 4 + r;
            const float inv = 1.0f / lsum[r];
            bf16* orow = o + (size_t)(b_ * 2048 + qq) * 2048 + h * 128;
#pragma unroll
            for (int nt2 = 0; nt2 < 8; ++nt2)
                orow[nt2 * 16 + r16] = (bf16)(oacc[nt2][r] * inv);
        }
    }
}

// ---------------------------------------------------------------------------
extern "C" void kernel_launch(void* const* d_in, const int* in_sizes, int n_in,
                              void* d_out, int out_size, void* d_ws, size_t ws_size,
                              hipStream_t stream) {
    const float* x    = (const float*)d_in[0];  // [4096][2048] fp32
    const float* Wqkv = (const float*)d_in[1];  // [2048][6144] fp32
    const float* Wo   = (const float*)d_in[2];  // [2048][2048] fp32
    float* out        = (float*)d_out;          // [4096][2048] fp32

    char* ws = (char*)d_ws;
    bf16* xb    = (bf16*)ws; ws += (size_t)4096 * 2048 * 2;
    bf16* WqkvT = (bf16*)ws; ws += (size_t)6144 * 2048 * 2;
    bf16* WoT   = (bf16*)ws; ws += (size_t)2048 * 2048 * 2;
    bf16* qt    = (bf16*)ws; ws += (size_t)32 * 2048 * 128 * 2;
    bf16* kt    = (bf16*)ws; ws += (size_t)32 * 2048 * 128 * 2;
    bf16* vt    = (bf16*)ws; ws += (size_t)32 * 128 * 2048 * 2;
    bf16* ob    = (bf16*)ws; ws += (size_t)4096 * 2048 * 2;

    downcast_kernel<<<8192, 256, 0, stream>>>(x, xb, (size_t)4096 * 2048);
    transpose_kernel<<<dim3(192, 64), 256, 0, stream>>>(Wqkv, WqkvT, 2048, 6144);
    transpose_kernel<<<dim3(64, 64), 256, 0, stream>>>(Wo, WoT, 2048, 2048);

    gemm_bt_kernel<0><<<dim3(48, 32), 256, 0, stream>>>(
        xb, WqkvT, 4096, 6144, 2048, qt, kt, vt, nullptr);

    attn_kernel<<<dim3(16, 32), 256, 0, stream>>>(qt, kt, vt, ob);

    gemm_bt_kernel<1><<<dim3(16, 32), 256, 0, stream>>>(
        ob, WoT, 4096, 2048, 2048, nullptr, nullptr, nullptr, out);
}